// Round 1
// baseline (266.078 us; speedup 1.0000x reference)
//
#include <hip/hip_runtime.h>
#include <hip/hip_bf16.h>

typedef __attribute__((ext_vector_type(8))) short short8;   // 8 bf16 = 4 VGPRs (MFMA A/B frag)
typedef __attribute__((ext_vector_type(4))) short short4v;  // 4 bf16 = 8 B
typedef __attribute__((ext_vector_type(4))) float floatx4;  // MFMA C/D frag

#define MFMA(a, b, c) __builtin_amdgcn_mfma_f32_16x16x32_bf16((a), (b), (c), 0, 0, 0)

// fp32 -> bf16, round-to-nearest-even (bit trick; inputs are finite)
__device__ __forceinline__ short f2bf(float f) {
    unsigned u = __float_as_uint(f);
    u += 0x7fffu + ((u >> 16) & 1u);
    return (short)(u >> 16);
}

// ---------------------------------------------------------------------------
// Cayley via Neumann/Horner series on one block (256 threads, 4 waves).
//   B = skew(X)/2 (entries ~0.01, ||B|| ~ 0.16)
//   C = (I-B)^-1 (I+B) = I + 2*(B + B^2 + ... )   truncated at K=10 terms
// Horner: S_1 = B;  S_{j+1} = B + B*S_j  (9 MFMA matmul steps)
// mode 0: write C row-major bf16 into outArr[row*72+col]          (B-operand use)
// mode 1: write C^T * diag bf16 into outArr[col*72+row] (A-operand use, diag folded)
// ---------------------------------------------------------------------------
__device__ void cayley64(const float* __restrict__ X, const float* __restrict__ dg,
                         short* outArr, int mode,
                         short* Brow, float* Bcol, short* T0, short* T1, int tid)
{
    // ---- init: B = skew(X)/2 into Brow (A-layout), Bcol (fp32, col-major), T0 (B-layout)
    int i0 = (tid * 16) >> 6;          // row, constant per thread
    int j0 = (tid * 16) & 63;          // 16-aligned col base
#pragma unroll
    for (int s = 0; s < 16; ++s) {
        int i = i0, j = j0 + s;
        float b = 0.f;
        if (i > j)      b =  0.5f * X[i * 64 + j];
        else if (i < j) b = -0.5f * X[j * 64 + i];
        Brow[i * 72 + j] = f2bf(b);
        Bcol[j * 68 + i] = b;
        T0[j * 72 + i]   = f2bf(b);
    }
    __syncthreads();

    int lane = tid & 63, w = tid >> 6, m = lane & 15, q = lane >> 4;
    int arow = (w * 16 + m) * 72;
    short8 a0 = *(const short8*)&Brow[arow + q * 8];        // A frag, k 0..31
    short8 a1 = *(const short8*)&Brow[arow + 32 + q * 8];   // A frag, k 32..63

    short* Tbuf[2] = {T0, T1};
    int cur = 0;
    const int NSTEP = 9;
    for (int step = 0; step < NSTEP; ++step) {
        bool last = (step == NSTEP - 1);
        short* Tr = Tbuf[cur];
        short* Tw = Tbuf[cur ^ 1];
#pragma unroll
        for (int c = 0; c < 4; ++c) {
            int coff = c * 16 + m;
            short8 b0 = *(const short8*)&Tr[coff * 72 + q * 8];
            short8 b1 = *(const short8*)&Tr[coff * 72 + 32 + q * 8];
            floatx4 acc = {0.f, 0.f, 0.f, 0.f};
            acc = MFMA(a0, b0, acc);
            acc = MFMA(a1, b1, acc);
            int row0 = w * 16 + q * 4;
            floatx4 badd = *(const floatx4*)&Bcol[coff * 68 + row0];
            floatx4 t = badd + acc;                 // T_new = B + B*T_old
            if (!last) {
                short4v pk = { f2bf(t.x), f2bf(t.y), f2bf(t.z), f2bf(t.w) };
                *(short4v*)&Tw[coff * 72 + row0] = pk;   // B-layout, b64 conflict-free
            } else {
                int col = coff;
                floatx4 cv;
                cv.x = ((row0 + 0) == col ? 1.f : 0.f) + 2.f * t.x;
                cv.y = ((row0 + 1) == col ? 1.f : 0.f) + 2.f * t.y;
                cv.z = ((row0 + 2) == col ? 1.f : 0.f) + 2.f * t.z;
                cv.w = ((row0 + 3) == col ? 1.f : 0.f) + 2.f * t.w;
                if (mode == 0) {
                    // row-major (B-operand array for compose)
                    outArr[(row0 + 0) * 72 + col] = f2bf(cv.x);
                    outArr[(row0 + 1) * 72 + col] = f2bf(cv.y);
                    outArr[(row0 + 2) * 72 + col] = f2bf(cv.z);
                    outArr[(row0 + 3) * 72 + col] = f2bf(cv.w);
                } else {
                    // C^T with diag folded (A-operand array for compose)
                    floatx4 dv = *(const floatx4*)&dg[row0];
                    short4v pk = { f2bf(cv.x * dv.x), f2bf(cv.y * dv.y),
                                   f2bf(cv.z * dv.z), f2bf(cv.w * dv.w) };
                    *(short4v*)&outArr[col * 72 + row0] = pk;
                }
            }
        }
        __syncthreads();
        cur ^= 1;
    }
}

// ---------------------------------------------------------------------------
// k_prep: 2 blocks. Block 0 -> m_left^T, block 1 -> m_right^T (bf16, row-major 64x64)
//   m^T = (Cv^T * diag) @ Cu^T   (one 64^3 MFMA matmul)
// ---------------------------------------------------------------------------
__global__ __launch_bounds__(256) void k_prep(
        const float* __restrict__ u_l, const float* __restrict__ v_l, const float* __restrict__ dg_l,
        const float* __restrict__ u_r, const float* __restrict__ v_r, const float* __restrict__ dg_r,
        short* __restrict__ wsOut)
{
    __shared__ __align__(16) short Brow[64 * 72];
    __shared__ __align__(16) float Bcol[64 * 68];
    __shared__ __align__(16) short T0[64 * 72];
    __shared__ __align__(16) short T1[64 * 72];
    __shared__ __align__(16) short CvA[64 * 72];  // A-operand: Cv^T * diag
    __shared__ __align__(16) short CuB[64 * 72];  // B-operand: Cu row-major

    int tid = threadIdx.x;
    const float* U  = (blockIdx.x == 0) ? u_l  : u_r;
    const float* V  = (blockIdx.x == 0) ? v_l  : v_r;
    const float* DG = (blockIdx.x == 0) ? dg_l : dg_r;
    short* outT = wsOut + blockIdx.x * 4096;

    cayley64(V, DG, CvA, 1, Brow, Bcol, T0, T1, tid);
    __syncthreads();
    cayley64(U, DG, CuB, 0, Brow, Bcol, T0, T1, tid);
    __syncthreads();

    // compose: m^T[j][i] = sum_k Cv[k][j]*diag[k]*Cu[i][k] = (CvA) @ (Cu^T)
    int lane = tid & 63, w = tid >> 6, m = lane & 15, q = lane >> 4;
    int arow = (w * 16 + m) * 72;
    short8 a0 = *(const short8*)&CvA[arow + q * 8];
    short8 a1 = *(const short8*)&CvA[arow + 32 + q * 8];
#pragma unroll
    for (int c = 0; c < 4; ++c) {
        short8 b0 = *(const short8*)&CuB[(c * 16 + m) * 72 + q * 8];
        short8 b1 = *(const short8*)&CuB[(c * 16 + m) * 72 + 32 + q * 8];
        floatx4 acc = {0.f, 0.f, 0.f, 0.f};
        acc = MFMA(a0, b0, acc);
        acc = MFMA(a1, b1, acc);
        int row0 = w * 16 + q * 4, col = c * 16 + m;
        outT[(row0 + 0) * 64 + col] = f2bf(acc.x);
        outT[(row0 + 1) * 64 + col] = f2bf(acc.y);
        outT[(row0 + 2) * 64 + col] = f2bf(acc.z);
        outT[(row0 + 3) * 64 + col] = f2bf(acc.w);
    }
}

// ---------------------------------------------------------------------------
// k_main: out_n = P @ (x_n * dscale) @ Q,  P = m_left^T, Q = m_right
// One block = 4 waves = one 64x64 matrix per inner step, NPB matrices per block.
// Stage 1: S = Xs @ Q  (Q^T frags in regs); S^T -> LDS (b64, conflict-free)
// Stage 2: out = P @ S (P frags in regs)
// ---------------------------------------------------------------------------
#define NPB 4

__global__ __launch_bounds__(256) void k_main(
        const float* __restrict__ x, const float* __restrict__ dsc,
        const short* __restrict__ mLT, const short* __restrict__ mRT,
        float* __restrict__ out, int N)
{
    __shared__ __align__(16) short Xs[64 * 72];
    __shared__ __align__(16) short ST[64 * 72];

    int tid = threadIdx.x;
    int lane = tid & 63, w = tid >> 6, m = lane & 15, q = tid >> 4 & 3;
    q = lane >> 4;

    // diag_scale: same 16 elements per thread for every n — preload
    floatx4 ds[4];
#pragma unroll
    for (int i = 0; i < 4; ++i) ds[i] = *(const floatx4*)&dsc[(i * 256 + tid) * 4];

    // P (A-operand) and Q^T (B-operand) fragments, resident in registers
    short8 pf0 = *(const short8*)&mLT[(w * 16 + m) * 64 + q * 8];
    short8 pf1 = *(const short8*)&mLT[(w * 16 + m) * 64 + 32 + q * 8];
    short8 qf[4][2];
#pragma unroll
    for (int c = 0; c < 4; ++c) {
        qf[c][0] = *(const short8*)&mRT[(c * 16 + m) * 64 + q * 8];
        qf[c][1] = *(const short8*)&mRT[(c * 16 + m) * 64 + 32 + q * 8];
    }

    for (int it = 0; it < NPB; ++it) {
        int n = blockIdx.x * NPB + it;
        if (n >= N) break;  // uniform per block
        const float* xp = x + (size_t)n * 4096;

        // ---- stage x*dscale -> LDS bf16 (coalesced 16B loads)
#pragma unroll
        for (int i = 0; i < 4; ++i) {
            int f = i * 256 + tid;
            floatx4 v = *(const floatx4*)&xp[f * 4];
            v = v * ds[i];
            int row = f >> 4, col = (f & 15) * 4;
            short4v pk = { f2bf(v.x), f2bf(v.y), f2bf(v.z), f2bf(v.w) };
            *(short4v*)&Xs[row * 72 + col] = pk;
        }
        __syncthreads();

        // ---- stage 1: S = Xs @ Q ; write S^T to LDS
        int arow = (w * 16 + m) * 72;
        short8 xa0 = *(const short8*)&Xs[arow + q * 8];
        short8 xa1 = *(const short8*)&Xs[arow + 32 + q * 8];
#pragma unroll
        for (int c = 0; c < 4; ++c) {
            floatx4 s = {0.f, 0.f, 0.f, 0.f};
            s = MFMA(xa0, qf[c][0], s);
            s = MFMA(xa1, qf[c][1], s);
            short4v pk = { f2bf(s.x), f2bf(s.y), f2bf(s.z), f2bf(s.w) };
            *(short4v*)&ST[(c * 16 + m) * 72 + w * 16 + q * 4] = pk;
        }
        __syncthreads();

        // ---- stage 2: out = P @ S
        float* op = out + (size_t)n * 4096;
#pragma unroll
        for (int c = 0; c < 4; ++c) {
            short8 sb0 = *(const short8*)&ST[(c * 16 + m) * 72 + q * 8];
            short8 sb1 = *(const short8*)&ST[(c * 16 + m) * 72 + 32 + q * 8];
            floatx4 o = {0.f, 0.f, 0.f, 0.f};
            o = MFMA(pf0, sb0, o);
            o = MFMA(pf1, sb1, o);
            int row0 = w * 16 + q * 4, col = c * 16 + m;
            op[(row0 + 0) * 64 + col] = o.x;
            op[(row0 + 1) * 64 + col] = o.y;
            op[(row0 + 2) * 64 + col] = o.z;
            op[(row0 + 3) * 64 + col] = o.w;
        }
        // no 3rd barrier needed: next-iter Xs writes are fenced by this iter's
        // post-stage1 barrier (Xs reads), and ST writes happen after next barrier A
    }
}

extern "C" void kernel_launch(void* const* d_in, const int* in_sizes, int n_in,
                              void* d_out, int out_size, void* d_ws, size_t ws_size,
                              hipStream_t stream) {
    const float* x    = (const float*)d_in[0];
    const float* u_l  = (const float*)d_in[1];
    const float* v_l  = (const float*)d_in[2];
    const float* dg_l = (const float*)d_in[3];
    const float* u_r  = (const float*)d_in[4];
    const float* v_r  = (const float*)d_in[5];
    const float* dg_r = (const float*)d_in[6];
    const float* dsc  = (const float*)d_in[7];
    float* out = (float*)d_out;
    short* ws  = (short*)d_ws;   // [0..4095]=m_left^T bf16, [4096..8191]=m_right^T bf16

    int N = in_sizes[0] / 4096;  // 8192 matrices of 64x64

    hipLaunchKernelGGL(k_prep, dim3(2), dim3(256), 0, stream,
                       u_l, v_l, dg_l, u_r, v_r, dg_r, ws);
    int grid = (N + NPB - 1) / NPB;
    hipLaunchKernelGGL(k_main, dim3(grid), dim3(256), 0, stream,
                       x, dsc, ws, ws + 4096, out, N);
}

// Round 2
// 262.579 us; speedup vs baseline: 1.0133x; 1.0133x over previous
//
#include <hip/hip_runtime.h>
#include <hip/hip_bf16.h>

typedef __attribute__((ext_vector_type(8))) short short8;   // 8 bf16 = 4 VGPRs (MFMA A/B frag)
typedef __attribute__((ext_vector_type(4))) short short4v;  // 4 bf16 = 8 B
typedef __attribute__((ext_vector_type(4))) float floatx4;  // MFMA C/D frag

#define MFMA(a, b, c) __builtin_amdgcn_mfma_f32_16x16x32_bf16((a), (b), (c), 0, 0, 0)

// fp32 -> bf16, round-to-nearest-even (bit trick; inputs are finite)
__device__ __forceinline__ short f2bf(float f) {
    unsigned u = __float_as_uint(f);
    u += 0x7fffu + ((u >> 16) & 1u);
    return (short)(u >> 16);
}

__device__ __forceinline__ short8 pack_bf16(floatx4 a, floatx4 b) {
    short8 r;
    r[0] = f2bf(a.x); r[1] = f2bf(a.y); r[2] = f2bf(a.z); r[3] = f2bf(a.w);
    r[4] = f2bf(b.x); r[5] = f2bf(b.y); r[6] = f2bf(b.z); r[7] = f2bf(b.w);
    return r;
}

// ---------------------------------------------------------------------------
// Cayley via Neumann/Horner series on one block (256 threads, 4 waves).
//   B = skew(X)/2 (||B||_2 ~ 0.16);  C = I + 2*(B + B^2 + ...)
// Horner: S_1 = B;  S_{j+1} = B + B*S_j.  NSTEP=6 -> truncation ~4e-5,
// far below bf16 rounding of C (~4e-3 relative).
// mode 0: write C row-major bf16 (B-operand array)
// mode 1: write C^T * diag bf16  (A-operand array, diag folded)
// ---------------------------------------------------------------------------
__device__ void cayley64(const float* __restrict__ X, const float* __restrict__ dg,
                         short* outArr, int mode,
                         short* Brow, float* Bcol, short* T0, short* T1, int tid)
{
    int i0 = (tid * 16) >> 6;
    int j0 = (tid * 16) & 63;
#pragma unroll
    for (int s = 0; s < 16; ++s) {
        int i = i0, j = j0 + s;
        float b = 0.f;
        if (i > j)      b =  0.5f * X[i * 64 + j];
        else if (i < j) b = -0.5f * X[j * 64 + i];
        Brow[i * 72 + j] = f2bf(b);
        Bcol[j * 68 + i] = b;
        T0[j * 72 + i]   = f2bf(b);
    }
    __syncthreads();

    int lane = tid & 63, w = tid >> 6, m = lane & 15, q = lane >> 4;
    int arow = (w * 16 + m) * 72;
    short8 a0 = *(const short8*)&Brow[arow + q * 8];
    short8 a1 = *(const short8*)&Brow[arow + 32 + q * 8];

    short* Tbuf[2] = {T0, T1};
    int cur = 0;
    const int NSTEP = 6;
    for (int step = 0; step < NSTEP; ++step) {
        bool last = (step == NSTEP - 1);
        short* Tr = Tbuf[cur];
        short* Tw = Tbuf[cur ^ 1];
#pragma unroll
        for (int c = 0; c < 4; ++c) {
            int coff = c * 16 + m;
            short8 b0 = *(const short8*)&Tr[coff * 72 + q * 8];
            short8 b1 = *(const short8*)&Tr[coff * 72 + 32 + q * 8];
            floatx4 acc = {0.f, 0.f, 0.f, 0.f};
            acc = MFMA(a0, b0, acc);
            acc = MFMA(a1, b1, acc);
            int row0 = w * 16 + q * 4;
            floatx4 badd = *(const floatx4*)&Bcol[coff * 68 + row0];
            floatx4 t = badd + acc;                 // T_new = B + B*T_old
            if (!last) {
                short4v pk = { f2bf(t.x), f2bf(t.y), f2bf(t.z), f2bf(t.w) };
                *(short4v*)&Tw[coff * 72 + row0] = pk;
            } else {
                int col = coff;
                floatx4 cv;
                cv.x = ((row0 + 0) == col ? 1.f : 0.f) + 2.f * t.x;
                cv.y = ((row0 + 1) == col ? 1.f : 0.f) + 2.f * t.y;
                cv.z = ((row0 + 2) == col ? 1.f : 0.f) + 2.f * t.z;
                cv.w = ((row0 + 3) == col ? 1.f : 0.f) + 2.f * t.w;
                if (mode == 0) {
                    outArr[(row0 + 0) * 72 + col] = f2bf(cv.x);
                    outArr[(row0 + 1) * 72 + col] = f2bf(cv.y);
                    outArr[(row0 + 2) * 72 + col] = f2bf(cv.z);
                    outArr[(row0 + 3) * 72 + col] = f2bf(cv.w);
                } else {
                    floatx4 dv = *(const floatx4*)&dg[row0];
                    short4v pk = { f2bf(cv.x * dv.x), f2bf(cv.y * dv.y),
                                   f2bf(cv.z * dv.z), f2bf(cv.w * dv.w) };
                    *(short4v*)&outArr[col * 72 + row0] = pk;
                }
            }
        }
        __syncthreads();
        cur ^= 1;
    }
}

// ---------------------------------------------------------------------------
// k_prep: 2 blocks. Block 0 -> m_left^T, block 1 -> m_right^T (bf16 row-major)
// ---------------------------------------------------------------------------
__global__ __launch_bounds__(256) void k_prep(
        const float* __restrict__ u_l, const float* __restrict__ v_l, const float* __restrict__ dg_l,
        const float* __restrict__ u_r, const float* __restrict__ v_r, const float* __restrict__ dg_r,
        short* __restrict__ wsOut)
{
    __shared__ __align__(16) short Brow[64 * 72];
    __shared__ __align__(16) float Bcol[64 * 68];
    __shared__ __align__(16) short T0[64 * 72];
    __shared__ __align__(16) short T1[64 * 72];
    __shared__ __align__(16) short CvA[64 * 72];
    __shared__ __align__(16) short CuB[64 * 72];

    int tid = threadIdx.x;
    const float* U  = (blockIdx.x == 0) ? u_l  : u_r;
    const float* V  = (blockIdx.x == 0) ? v_l  : v_r;
    const float* DG = (blockIdx.x == 0) ? dg_l : dg_r;
    short* outT = wsOut + blockIdx.x * 4096;

    cayley64(V, DG, CvA, 1, Brow, Bcol, T0, T1, tid);
    __syncthreads();
    cayley64(U, DG, CuB, 0, Brow, Bcol, T0, T1, tid);
    __syncthreads();

    int lane = tid & 63, w = tid >> 6, m = lane & 15, q = lane >> 4;
    int arow = (w * 16 + m) * 72;
    short8 a0 = *(const short8*)&CvA[arow + q * 8];
    short8 a1 = *(const short8*)&CvA[arow + 32 + q * 8];
#pragma unroll
    for (int c = 0; c < 4; ++c) {
        short8 b0 = *(const short8*)&CuB[(c * 16 + m) * 72 + q * 8];
        short8 b1 = *(const short8*)&CuB[(c * 16 + m) * 72 + 32 + q * 8];
        floatx4 acc = {0.f, 0.f, 0.f, 0.f};
        acc = MFMA(a0, b0, acc);
        acc = MFMA(a1, b1, acc);
        int row0 = w * 16 + q * 4, col = c * 16 + m;
        outT[(row0 + 0) * 64 + col] = f2bf(acc.x);
        outT[(row0 + 1) * 64 + col] = f2bf(acc.y);
        outT[(row0 + 2) * 64 + col] = f2bf(acc.z);
        outT[(row0 + 3) * 64 + col] = f2bf(acc.w);
    }
}

// ---------------------------------------------------------------------------
// k_main v2: out_n = P @ (x_n * dscale) @ Q
//  - A-frags of Xs loaded DIRECTLY from global (rows are 32B-contiguous in x)
//  - software pipeline: iter n+1's x loads issued before iter n's compute
//  - S^T transpose double-buffered in LDS -> 1 barrier per matrix
// ---------------------------------------------------------------------------
#define NPB 4

__global__ __launch_bounds__(256) void k_main(
        const float* __restrict__ x, const float* __restrict__ dsc,
        const short* __restrict__ mLT, const short* __restrict__ mRT,
        float* __restrict__ out, int N)
{
    __shared__ __align__(16) short ST[2][64 * 72];

    int tid = threadIdx.x;
    int lane = tid & 63, w = tid >> 6, m = lane & 15, q = lane >> 4;
    const int rowoff = (w * 16 + m) * 64 + q * 8;  // element offset of this lane's A-frag

    // dscale at this lane's fixed A-frag positions (constant across n)
    floatx4 ds0a = *(const floatx4*)&dsc[rowoff];
    floatx4 ds0b = *(const floatx4*)&dsc[rowoff + 4];
    floatx4 ds1a = *(const floatx4*)&dsc[rowoff + 32];
    floatx4 ds1b = *(const floatx4*)&dsc[rowoff + 36];

    // P (A-operand) and Q^T (B-operand) fragments resident in registers
    short8 pf0 = *(const short8*)&mLT[(w * 16 + m) * 64 + q * 8];
    short8 pf1 = *(const short8*)&mLT[(w * 16 + m) * 64 + 32 + q * 8];
    short8 qf[4][2];
#pragma unroll
    for (int c = 0; c < 4; ++c) {
        qf[c][0] = *(const short8*)&mRT[(c * 16 + m) * 64 + q * 8];
        qf[c][1] = *(const short8*)&mRT[(c * 16 + m) * 64 + 32 + q * 8];
    }

    const int base = blockIdx.x * NPB;
    const float* xb = x + (size_t)base * 4096 + rowoff;

    // prefetch iter 0
    floatx4 xr0, xr1, xr2, xr3;
    if (base < N) {
        xr0 = *(const floatx4*)&xb[0];
        xr1 = *(const floatx4*)&xb[4];
        xr2 = *(const floatx4*)&xb[32];
        xr3 = *(const floatx4*)&xb[36];
    }

#pragma unroll
    for (int it = 0; it < NPB; ++it) {
        int n = base + it;
        if (n >= N) break;  // uniform per block

        // ---- prefetch next matrix while computing this one
        floatx4 nx0, nx1, nx2, nx3;
        bool pf = (it + 1 < NPB) && (n + 1 < N);
        if (pf) {
            const float* xn = xb + (size_t)(it + 1) * 4096;
            nx0 = *(const floatx4*)&xn[0];
            nx1 = *(const floatx4*)&xn[4];
            nx2 = *(const floatx4*)&xn[32];
            nx3 = *(const floatx4*)&xn[36];
        }

        // ---- scale + convert A-frags in registers
        short8 xa0 = pack_bf16(xr0 * ds0a, xr1 * ds0b);   // k = 0..31
        short8 xa1 = pack_bf16(xr2 * ds1a, xr3 * ds1b);   // k = 32..63

        // ---- stage 1: S = Xs @ Q ; write S^T to LDS (buf it&1)
        short* STw = ST[it & 1];
#pragma unroll
        for (int c = 0; c < 4; ++c) {
            floatx4 s = {0.f, 0.f, 0.f, 0.f};
            s = MFMA(xa0, qf[c][0], s);
            s = MFMA(xa1, qf[c][1], s);
            short4v pk = { f2bf(s.x), f2bf(s.y), f2bf(s.z), f2bf(s.w) };
            *(short4v*)&STw[(c * 16 + m) * 72 + w * 16 + q * 4] = pk;
        }
        __syncthreads();

        // ---- stage 2: out = P @ S
        float* op = out + (size_t)n * 4096;
#pragma unroll
        for (int c = 0; c < 4; ++c) {
            short8 sb0 = *(const short8*)&STw[(c * 16 + m) * 72 + q * 8];
            short8 sb1 = *(const short8*)&STw[(c * 16 + m) * 72 + 32 + q * 8];
            floatx4 o = {0.f, 0.f, 0.f, 0.f};
            o = MFMA(pf0, sb0, o);
            o = MFMA(pf1, sb1, o);
            int row0 = w * 16 + q * 4, col = c * 16 + m;
            op[(row0 + 0) * 64 + col] = o.x;
            op[(row0 + 1) * 64 + col] = o.y;
            op[(row0 + 2) * 64 + col] = o.z;
            op[(row0 + 3) * 64 + col] = o.w;
        }
        // rotate pipeline registers
        if (pf) { xr0 = nx0; xr1 = nx1; xr2 = nx2; xr3 = nx3; }
        // no second barrier: next iter writes the OTHER ST buffer; reuse of this
        // buffer (it+2) is fenced by the barrier at it+1.
    }
}

extern "C" void kernel_launch(void* const* d_in, const int* in_sizes, int n_in,
                              void* d_out, int out_size, void* d_ws, size_t ws_size,
                              hipStream_t stream) {
    const float* x    = (const float*)d_in[0];
    const float* u_l  = (const float*)d_in[1];
    const float* v_l  = (const float*)d_in[2];
    const float* dg_l = (const float*)d_in[3];
    const float* u_r  = (const float*)d_in[4];
    const float* v_r  = (const float*)d_in[5];
    const float* dg_r = (const float*)d_in[6];
    const float* dsc  = (const float*)d_in[7];
    float* out = (float*)d_out;
    short* ws  = (short*)d_ws;   // [0..4095]=m_left^T bf16, [4096..8191]=m_right^T bf16

    int N = in_sizes[0] / 4096;  // 8192 matrices of 64x64

    hipLaunchKernelGGL(k_prep, dim3(2), dim3(256), 0, stream,
                       u_l, v_l, dg_l, u_r, v_r, dg_r, ws);
    int grid = (N + NPB - 1) / NPB;
    hipLaunchKernelGGL(k_main, dim3(grid), dim3(256), 0, stream,
                       x, dsc, ws, ws + 4096, out, N);
}

// Round 3
// 262.249 us; speedup vs baseline: 1.0146x; 1.0013x over previous
//
#include <hip/hip_runtime.h>
#include <hip/hip_bf16.h>

typedef __attribute__((ext_vector_type(8))) short short8;   // 8 bf16 = 4 VGPRs (MFMA A/B frag)
typedef __attribute__((ext_vector_type(4))) short short4v;  // 4 bf16 = 8 B
typedef __attribute__((ext_vector_type(4))) float floatx4;  // MFMA C/D frag

#define MFMA(a, b, c) __builtin_amdgcn_mfma_f32_16x16x32_bf16((a), (b), (c), 0, 0, 0)

// Barrier that waits only on LDS ops (lgkmcnt), NOT global vmcnt: keeps
// prefetched x loads and out stores in flight across iterations. The
// compiler's __syncthreads() emits s_waitcnt vmcnt(0) before s_barrier,
// which serialized every iteration on a full HBM round trip (R0/R1 both
// pinned at ~2.4 TB/s regardless of structure — this drain was the cause).
#define BARRIER_LDS() asm volatile("s_waitcnt lgkmcnt(0)\n\ts_barrier" ::: "memory")

// fp32 -> bf16, round-to-nearest-even (bit trick; inputs are finite)
__device__ __forceinline__ short f2bf(float f) {
    unsigned u = __float_as_uint(f);
    u += 0x7fffu + ((u >> 16) & 1u);
    return (short)(u >> 16);
}

__device__ __forceinline__ short8 pack_bf16(floatx4 a, floatx4 b) {
    short8 r;
    r[0] = f2bf(a.x); r[1] = f2bf(a.y); r[2] = f2bf(a.z); r[3] = f2bf(a.w);
    r[4] = f2bf(b.x); r[5] = f2bf(b.y); r[6] = f2bf(b.z); r[7] = f2bf(b.w);
    return r;
}

// ---------------------------------------------------------------------------
// Cayley via Neumann/Horner series on one block (256 threads, 4 waves).
//   B = skew(X)/2 (||B||_2 ~ 0.16);  C = I + 2*(B + B^2 + ...)
// NSTEP=6 -> truncation ~4e-5, far below bf16 rounding.
// mode 0: write C row-major bf16 (B-operand array)
// mode 1: write C^T * diag bf16  (A-operand array, diag folded)
// ---------------------------------------------------------------------------
__device__ void cayley64(const float* __restrict__ X, const float* __restrict__ dg,
                         short* outArr, int mode,
                         short* Brow, float* Bcol, short* T0, short* T1, int tid)
{
    int i0 = (tid * 16) >> 6;
    int j0 = (tid * 16) & 63;
#pragma unroll
    for (int s = 0; s < 16; ++s) {
        int i = i0, j = j0 + s;
        float b = 0.f;
        if (i > j)      b =  0.5f * X[i * 64 + j];
        else if (i < j) b = -0.5f * X[j * 64 + i];
        Brow[i * 72 + j] = f2bf(b);
        Bcol[j * 68 + i] = b;
        T0[j * 72 + i]   = f2bf(b);
    }
    __syncthreads();

    int lane = tid & 63, w = tid >> 6, m = lane & 15, q = lane >> 4;
    int arow = (w * 16 + m) * 72;
    short8 a0 = *(const short8*)&Brow[arow + q * 8];
    short8 a1 = *(const short8*)&Brow[arow + 32 + q * 8];

    short* Tbuf[2] = {T0, T1};
    int cur = 0;
    const int NSTEP = 6;
    for (int step = 0; step < NSTEP; ++step) {
        bool last = (step == NSTEP - 1);
        short* Tr = Tbuf[cur];
        short* Tw = Tbuf[cur ^ 1];
#pragma unroll
        for (int c = 0; c < 4; ++c) {
            int coff = c * 16 + m;
            short8 b0 = *(const short8*)&Tr[coff * 72 + q * 8];
            short8 b1 = *(const short8*)&Tr[coff * 72 + 32 + q * 8];
            floatx4 acc = {0.f, 0.f, 0.f, 0.f};
            acc = MFMA(a0, b0, acc);
            acc = MFMA(a1, b1, acc);
            int row0 = w * 16 + q * 4;
            floatx4 badd = *(const floatx4*)&Bcol[coff * 68 + row0];
            floatx4 t = badd + acc;                 // T_new = B + B*T_old
            if (!last) {
                short4v pk = { f2bf(t.x), f2bf(t.y), f2bf(t.z), f2bf(t.w) };
                *(short4v*)&Tw[coff * 72 + row0] = pk;
            } else {
                int col = coff;
                floatx4 cv;
                cv.x = ((row0 + 0) == col ? 1.f : 0.f) + 2.f * t.x;
                cv.y = ((row0 + 1) == col ? 1.f : 0.f) + 2.f * t.y;
                cv.z = ((row0 + 2) == col ? 1.f : 0.f) + 2.f * t.z;
                cv.w = ((row0 + 3) == col ? 1.f : 0.f) + 2.f * t.w;
                if (mode == 0) {
                    outArr[(row0 + 0) * 72 + col] = f2bf(cv.x);
                    outArr[(row0 + 1) * 72 + col] = f2bf(cv.y);
                    outArr[(row0 + 2) * 72 + col] = f2bf(cv.z);
                    outArr[(row0 + 3) * 72 + col] = f2bf(cv.w);
                } else {
                    floatx4 dv = *(const floatx4*)&dg[row0];
                    short4v pk = { f2bf(cv.x * dv.x), f2bf(cv.y * dv.y),
                                   f2bf(cv.z * dv.z), f2bf(cv.w * dv.w) };
                    *(short4v*)&outArr[col * 72 + row0] = pk;
                }
            }
        }
        __syncthreads();
        cur ^= 1;
    }
}

// ---------------------------------------------------------------------------
// k_prep: 2 blocks. Block 0 -> m_left^T, block 1 -> m_right^T (bf16 row-major)
// ---------------------------------------------------------------------------
__global__ __launch_bounds__(256) void k_prep(
        const float* __restrict__ u_l, const float* __restrict__ v_l, const float* __restrict__ dg_l,
        const float* __restrict__ u_r, const float* __restrict__ v_r, const float* __restrict__ dg_r,
        short* __restrict__ wsOut)
{
    __shared__ __align__(16) short Brow[64 * 72];
    __shared__ __align__(16) float Bcol[64 * 68];
    __shared__ __align__(16) short T0[64 * 72];
    __shared__ __align__(16) short T1[64 * 72];
    __shared__ __align__(16) short CvA[64 * 72];
    __shared__ __align__(16) short CuB[64 * 72];

    int tid = threadIdx.x;
    const float* U  = (blockIdx.x == 0) ? u_l  : u_r;
    const float* V  = (blockIdx.x == 0) ? v_l  : v_r;
    const float* DG = (blockIdx.x == 0) ? dg_l : dg_r;
    short* outT = wsOut + blockIdx.x * 4096;

    cayley64(V, DG, CvA, 1, Brow, Bcol, T0, T1, tid);
    __syncthreads();
    cayley64(U, DG, CuB, 0, Brow, Bcol, T0, T1, tid);
    __syncthreads();

    int lane = tid & 63, w = tid >> 6, m = lane & 15, q = lane >> 4;
    int arow = (w * 16 + m) * 72;
    short8 a0 = *(const short8*)&CvA[arow + q * 8];
    short8 a1 = *(const short8*)&CvA[arow + 32 + q * 8];
#pragma unroll
    for (int c = 0; c < 4; ++c) {
        short8 b0 = *(const short8*)&CuB[(c * 16 + m) * 72 + q * 8];
        short8 b1 = *(const short8*)&CuB[(c * 16 + m) * 72 + 32 + q * 8];
        floatx4 acc = {0.f, 0.f, 0.f, 0.f};
        acc = MFMA(a0, b0, acc);
        acc = MFMA(a1, b1, acc);
        int row0 = w * 16 + q * 4, col = c * 16 + m;
        outT[(row0 + 0) * 64 + col] = f2bf(acc.x);
        outT[(row0 + 1) * 64 + col] = f2bf(acc.y);
        outT[(row0 + 2) * 64 + col] = f2bf(acc.z);
        outT[(row0 + 3) * 64 + col] = f2bf(acc.w);
    }
}

// ---------------------------------------------------------------------------
// k_main v3: out_n = P @ (x_n * dscale) @ Q
//  - A-frags of x loaded directly from global, register-pipelined 1 matrix deep
//  - S^T transpose double-buffered in LDS, ONE barrier per matrix
//  - barrier is lgkmcnt-only (no vmcnt drain) -> loads/stores stay in flight
// ---------------------------------------------------------------------------
#define NPB 4

__global__ __launch_bounds__(256) void k_main(
        const float* __restrict__ x, const float* __restrict__ dsc,
        const short* __restrict__ mLT, const short* __restrict__ mRT,
        float* __restrict__ out, int N)
{
    __shared__ __align__(16) short ST[2][64 * 72];

    int tid = threadIdx.x;
    int lane = tid & 63, w = tid >> 6, m = lane & 15, q = lane >> 4;
    const int rowoff = (w * 16 + m) * 64 + q * 8;  // element offset of this lane's A-frag

    // dscale at this lane's fixed A-frag positions (constant across n)
    floatx4 ds0a = *(const floatx4*)&dsc[rowoff];
    floatx4 ds0b = *(const floatx4*)&dsc[rowoff + 4];
    floatx4 ds1a = *(const floatx4*)&dsc[rowoff + 32];
    floatx4 ds1b = *(const floatx4*)&dsc[rowoff + 36];

    // P (A-operand) and Q^T (B-operand) fragments resident in registers
    short8 pf0 = *(const short8*)&mLT[(w * 16 + m) * 64 + q * 8];
    short8 pf1 = *(const short8*)&mLT[(w * 16 + m) * 64 + 32 + q * 8];
    short8 qf[4][2];
#pragma unroll
    for (int c = 0; c < 4; ++c) {
        qf[c][0] = *(const short8*)&mRT[(c * 16 + m) * 64 + q * 8];
        qf[c][1] = *(const short8*)&mRT[(c * 16 + m) * 64 + 32 + q * 8];
    }

    const int base = blockIdx.x * NPB;
    const float* xb = x + (size_t)base * 4096 + rowoff;

    // prefetch iter 0
    floatx4 xr0, xr1, xr2, xr3;
    if (base < N) {
        xr0 = *(const floatx4*)&xb[0];
        xr1 = *(const floatx4*)&xb[4];
        xr2 = *(const floatx4*)&xb[32];
        xr3 = *(const floatx4*)&xb[36];
    }

#pragma unroll
    for (int it = 0; it < NPB; ++it) {
        int n = base + it;
        if (n >= N) break;  // uniform per block

        // ---- prefetch next matrix while computing this one
        floatx4 nx0, nx1, nx2, nx3;
        bool pf = (it + 1 < NPB) && (n + 1 < N);
        if (pf) {
            const float* xn = xb + (size_t)(it + 1) * 4096;
            nx0 = *(const floatx4*)&xn[0];
            nx1 = *(const floatx4*)&xn[4];
            nx2 = *(const floatx4*)&xn[32];
            nx3 = *(const floatx4*)&xn[36];
        }

        // ---- scale + convert A-frags in registers
        short8 xa0 = pack_bf16(xr0 * ds0a, xr1 * ds0b);   // k = 0..31
        short8 xa1 = pack_bf16(xr2 * ds1a, xr3 * ds1b);   // k = 32..63

        // ---- stage 1: S = Xs @ Q ; write S^T to LDS (buf it&1)
        short* STw = ST[it & 1];
#pragma unroll
        for (int c = 0; c < 4; ++c) {
            floatx4 s = {0.f, 0.f, 0.f, 0.f};
            s = MFMA(xa0, qf[c][0], s);
            s = MFMA(xa1, qf[c][1], s);
            short4v pk = { f2bf(s.x), f2bf(s.y), f2bf(s.z), f2bf(s.w) };
            *(short4v*)&STw[(c * 16 + m) * 72 + w * 16 + q * 4] = pk;
        }
        BARRIER_LDS();   // lgkmcnt-only: prefetch + prior stores stay in flight

        // ---- stage 2: out = P @ S
        float* op = out + (size_t)n * 4096;
#pragma unroll
        for (int c = 0; c < 4; ++c) {
            short8 sb0 = *(const short8*)&STw[(c * 16 + m) * 72 + q * 8];
            short8 sb1 = *(const short8*)&STw[(c * 16 + m) * 72 + 32 + q * 8];
            floatx4 o = {0.f, 0.f, 0.f, 0.f};
            o = MFMA(pf0, sb0, o);
            o = MFMA(pf1, sb1, o);
            int row0 = w * 16 + q * 4, col = c * 16 + m;
            op[(row0 + 0) * 64 + col] = o.x;
            op[(row0 + 1) * 64 + col] = o.y;
            op[(row0 + 2) * 64 + col] = o.z;
            op[(row0 + 3) * 64 + col] = o.w;
        }
        // rotate pipeline registers
        if (pf) { xr0 = nx0; xr1 = nx1; xr2 = nx2; xr3 = nx3; }
        // buffer reuse at it+2 is fenced by the barrier at it+1 (all waves must
        // have finished this iter's stage-2 LDS reads to reach that barrier).
    }
}

extern "C" void kernel_launch(void* const* d_in, const int* in_sizes, int n_in,
                              void* d_out, int out_size, void* d_ws, size_t ws_size,
                              hipStream_t stream) {
    const float* x    = (const float*)d_in[0];
    const float* u_l  = (const float*)d_in[1];
    const float* v_l  = (const float*)d_in[2];
    const float* dg_l = (const float*)d_in[3];
    const float* u_r  = (const float*)d_in[4];
    const float* v_r  = (const float*)d_in[5];
    const float* dg_r = (const float*)d_in[6];
    const float* dsc  = (const float*)d_in[7];
    float* out = (float*)d_out;
    short* ws  = (short*)d_ws;   // [0..4095]=m_left^T bf16, [4096..8191]=m_right^T bf16

    int N = in_sizes[0] / 4096;  // 8192 matrices of 64x64

    hipLaunchKernelGGL(k_prep, dim3(2), dim3(256), 0, stream,
                       u_l, v_l, dg_l, u_r, v_r, dg_r, ws);
    int grid = (N + NPB - 1) / NPB;
    hipLaunchKernelGGL(k_main, dim3(grid), dim3(256), 0, stream,
                       x, dsc, ws, ws + 4096, out, N);
}